// Round 2
// baseline (593.178 us; speedup 1.0000x reference)
//
#include <hip/hip_runtime.h>

typedef unsigned short u16;
typedef unsigned int u32;
typedef __bf16 bf16x8 __attribute__((ext_vector_type(8)));
typedef float f32x4 __attribute__((ext_vector_type(4)));

__device__ __forceinline__ u16 f2b(float f) {
  u32 u = __builtin_bit_cast(u32, f);
  u32 r = (u + 0x7fffu + ((u >> 16) & 1u)) >> 16;  // RNE
  return (u16)r;
}
__device__ __forceinline__ bf16x8 ld_frag(const u16* p) {
  uint4 v = *(const uint4*)p;
  return __builtin_bit_cast(bf16x8, v);
}
__device__ __forceinline__ void async_lds16(const u16* g, u16* lds) {
  __builtin_amdgcn_global_load_lds(
      (const __attribute__((address_space(1))) void*)g,
      (__attribute__((address_space(3))) void*)lds, 16, 0, 0);
}
// wait lgkmcnt(0) only (vmcnt=63, expcnt=7 untouched)
__device__ __forceinline__ void wait_lds() { __builtin_amdgcn_s_waitcnt(0xc07f); }

// ---------------- fp32 -> bf16 bulk convert (x) ----------------
__global__ __launch_bounds__(256) void convert_f32_bf16(const float* __restrict__ in,
                                                        u16* __restrict__ out) {
  long i = ((long)blockIdx.x * 256 + threadIdx.x) * 8;
  float4 a = *(const float4*)(in + i);
  float4 b = *(const float4*)(in + i + 4);
  union { uint4 v; u16 e[8]; } u;
  u.e[0] = f2b(a.x); u.e[1] = f2b(a.y); u.e[2] = f2b(a.z); u.e[3] = f2b(a.w);
  u.e[4] = f2b(b.x); u.e[5] = f2b(b.y); u.e[6] = f2b(b.z); u.e[7] = f2b(b.w);
  *(uint4*)(out + i) = u.v;
}

// ---------------- weight transpose+convert: W_f32[K][N] -> Wt_bf16[N][K] ----------------
__global__ __launch_bounds__(256) void transpose_w(const float* __restrict__ W,
                                                   u16* __restrict__ Wt,
                                                   int K, int N) {
  __shared__ alignas(16) u16 T[64][80];
  const int n0 = blockIdx.x * 64, k0 = blockIdx.y * 64;
  const int t = threadIdx.x;
  {
    int kk = t >> 3, c = t & 7;
#pragma unroll
    for (int rr = 0; rr < 2; ++rr) {
      int kr = kk + rr * 32;
      const float* src = W + (long)(k0 + kr) * N + n0 + c * 8;
      float4 a = *(const float4*)src;
      float4 b = *(const float4*)(src + 4);
      u16* dst = &T[kr][c * 8];
      dst[0] = f2b(a.x); dst[1] = f2b(a.y); dst[2] = f2b(a.z); dst[3] = f2b(a.w);
      dst[4] = f2b(b.x); dst[5] = f2b(b.y); dst[6] = f2b(b.z); dst[7] = f2b(b.w);
    }
  }
  __syncthreads();
  {
    int nn = t >> 3, kc = t & 7;
#pragma unroll
    for (int rr = 0; rr < 2; ++rr) {
      int nr = nn + rr * 32;
      union { uint4 v; u16 e[8]; } u;
#pragma unroll
      for (int i = 0; i < 8; ++i) u.e[i] = T[kc * 8 + i][nr];
      *(uint4*)(Wt + (long)(n0 + nr) * K + k0 + kc * 8) = u.v;
    }
  }
}

// ---------------- pipelined GEMM: C[M][N] = A_bf16[M][K] * Bt_bf16[N][K]^T + bias ----------------
// BM=256 BN=128 BK=32; 4 waves (2M x 2N), per-wave 128x64 (acc[8][4]) -> per-CU
// LDS-read cycles (1152) ~ MFMA cycles (1032): balanced pipes.
// LDS ring of 3 K-tile slots (24 KiB each = 72 KiB) -> 2 blocks/CU: independent
// blocks decouple barrier stalls.
// Software pipeline, one barrier per K-tile:
//   P1: issue ds_reads A-hi[t]; stage 3/6 of tile t+2; MFMA mt0-3 (uses pre-read B,A-lo)
//   P2: vmcnt(3) gate (t+1 landed, never 0 mid-loop); lgkmcnt(0); s_barrier;
//       pre-read B[t+1],A-lo[t+1]; stage 3/6 of t+2; MFMA mt4-7 (uses A-hi)
// Race-freedom: lgkmcnt(0)+barrier at P2(t) proves all reads of slot (t%3) done
// before any wave issues tile t+3 staging (P1(t+1)); ring-3 separates by 2 tiles.
// Rows are 64B; 16B chunks XOR-swizzled by (row&3) via inverse-swizzled global src.
template <bool OUT_F32>
__global__ __launch_bounds__(256, 2) void gemm_pipe(const u16* __restrict__ A,
                                                    const u16* __restrict__ Bt,
                                                    const float* __restrict__ bias,
                                                    void* __restrict__ Cv,
                                                    int M, int N, int K) {
  __shared__ alignas(16) u16 lds[3 * 12288];  // 3 x 24 KiB; slot: A [256][32] @0, B [128][32] @8192
  const int tid = threadIdx.x;
  const int lane = tid & 63, wave = tid >> 6;
  const int quad = lane >> 4, ln = lane & 15;
  const int wm = wave >> 1, wn = wave & 1;  // per-wave 128x64 tile

  // XCD-aware bijective swizzle (nwg % 8 == 0 for both launches)
  const int nwg = gridDim.x;
  const int bid = blockIdx.x;
  const int wg = (bid & 7) * (nwg >> 3) + (bid >> 3);
  const int ntn = N >> 7;
  const int tn = wg % ntn, tm = wg / ntn;
  const long m0 = (long)tm * 256;
  const long n0 = (long)tn * 128;

  // staging: one global_load_lds covers 1024B = 16 rows x 64B. unit u covers
  // rows [u*64 + wave*16, +16); lane: row += lane>>2, chunk lane&3 (inv-swizzled).
  const int srow = lane >> 2;
  const int swz = ((lane & 3) ^ (srow & 3)) * 8;
  const u16* gA[4];
  const u16* gB[2];
#pragma unroll
  for (int u = 0; u < 4; ++u) gA[u] = A + (long)(m0 + u * 64 + wave * 16 + srow) * K + swz;
#pragma unroll
  for (int v = 0; v < 2; ++v) gB[v] = Bt + (long)(n0 + v * 64 + wave * 16 + srow) * K + swz;

  const int KT = K >> 5;

  auto stageP1 = [&](int t) {  // A units 0..2
    if (t >= KT) return;
    u16* s = &lds[(t % 3) * 12288 + wave * 512];
    long ko = (long)t * 32;
    async_lds16(gA[0] + ko, s);
    async_lds16(gA[1] + ko, s + 2048);
    async_lds16(gA[2] + ko, s + 4096);
  };
  auto stageP2 = [&](int t) {  // A unit 3 + B units
    if (t >= KT) return;
    u16* s = &lds[(t % 3) * 12288 + wave * 512];
    long ko = (long)t * 32;
    async_lds16(gA[3] + ko, s + 6144);
    async_lds16(gB[0] + ko, s + 8192);
    async_lds16(gB[1] + ko, s + 8192 + 2048);
  };

  const int cswz = (quad ^ (ln & 3)) * 8;  // matching read-side XOR (row&3 == ln&3)
  auto ldA = [&](int t, int mt) {
    int row = wm * 128 + mt * 16 + ln;
    return ld_frag(&lds[(t % 3) * 12288 + row * 32 + cswz]);
  };
  auto ldB = [&](int t, int nt) {
    int row = wn * 64 + nt * 16 + ln;
    return ld_frag(&lds[(t % 3) * 12288 + 8192 + row * 32 + cswz]);
  };

  f32x4 zero = {0.f, 0.f, 0.f, 0.f};
  f32x4 acc[8][4];
#pragma unroll
  for (int i = 0; i < 8; ++i)
#pragma unroll
    for (int j = 0; j < 4; ++j) acc[i][j] = zero;

  // prologue: stage tiles 0,1; wait tile 0 landed (tile 1's 6 may fly)
  stageP1(0); stageP2(0);
  stageP1(1); stageP2(1);
  __builtin_amdgcn_s_waitcnt(0x0f76);  // vmcnt(6)
  __builtin_amdgcn_s_barrier();

  bf16x8 bf[4], alo[4], ahi[4];
#pragma unroll
  for (int nt = 0; nt < 4; ++nt) bf[nt] = ldB(0, nt);
#pragma unroll
  for (int mt = 0; mt < 4; ++mt) alo[mt] = ldA(0, mt);

  for (int t = 0; t < KT; ++t) {
    // ---- P1: issue A-hi reads, stage, MFMA lower half ----
#pragma unroll
    for (int mt = 0; mt < 4; ++mt) ahi[mt] = ldA(t, mt + 4);
    stageP1(t + 2);
#pragma unroll
    for (int mt = 0; mt < 4; ++mt)
#pragma unroll
      for (int nt = 0; nt < 4; ++nt)
        acc[mt][nt] = __builtin_amdgcn_mfma_f32_16x16x32_bf16(alo[mt], bf[nt], acc[mt][nt], 0, 0, 0);
    // ---- P2: gate, barrier, pre-read next tile, stage, MFMA upper half ----
    if (t + 1 < KT) {
      if (t + 2 < KT) __builtin_amdgcn_s_waitcnt(0x0f73);  // vmcnt(3): tile t+1 landed
      else            __builtin_amdgcn_s_waitcnt(0x0f70);  // vmcnt(0): tail drain
      wait_lds();                    // lgkmcnt(0): ALL my ds_reads of slots <= t complete
      __builtin_amdgcn_s_barrier();  // => slot (t%3) fully read; tile t+1 fully landed
      bf16x8 nbf[4], nalo[4];
#pragma unroll
      for (int nt = 0; nt < 4; ++nt) nbf[nt] = ldB(t + 1, nt);
#pragma unroll
      for (int mt = 0; mt < 4; ++mt) nalo[mt] = ldA(t + 1, mt);
      stageP2(t + 2);
#pragma unroll
      for (int mt = 0; mt < 4; ++mt)
#pragma unroll
        for (int nt = 0; nt < 4; ++nt)
          acc[mt + 4][nt] = __builtin_amdgcn_mfma_f32_16x16x32_bf16(ahi[mt], bf[nt], acc[mt + 4][nt], 0, 0, 0);
#pragma unroll
      for (int nt = 0; nt < 4; ++nt) bf[nt] = nbf[nt];
#pragma unroll
      for (int mt = 0; mt < 4; ++mt) alo[mt] = nalo[mt];
    } else {
#pragma unroll
      for (int mt = 0; mt < 4; ++mt)
#pragma unroll
        for (int nt = 0; nt < 4; ++nt)
          acc[mt + 4][nt] = __builtin_amdgcn_mfma_f32_16x16x32_bf16(ahi[mt], bf[nt], acc[mt + 4][nt], 0, 0, 0);
    }
  }

  __syncthreads();  // full drain before LDS reuse by epilogue

  if (OUT_F32) {
#pragma unroll
    for (int nt = 0; nt < 4; ++nt) {
      long coln = n0 + wn * 64 + nt * 16 + ln;
      float bv = bias[coln];
#pragma unroll
      for (int mt = 0; mt < 8; ++mt) {
        long rowb = m0 + wm * 128 + mt * 16 + quad * 4;
#pragma unroll
        for (int r = 0; r < 4; ++r)
          ((float*)Cv)[(rowb + r) * N + coln] = acc[mt][nt][r] + bv;
      }
    }
  } else {
    // bf16: wave-private LDS patch for full-line 16B stores
    u16* patch = &lds[wave * 2176];  // [16][136]
    float bv[4];
#pragma unroll
    for (int nt = 0; nt < 4; ++nt) bv[nt] = bias[n0 + wn * 64 + nt * 16 + ln];
#pragma unroll
    for (int mt = 0; mt < 8; ++mt) {
#pragma unroll
      for (int nt = 0; nt < 4; ++nt)
#pragma unroll
        for (int r = 0; r < 4; ++r)
          patch[(quad * 4 + r) * 136 + nt * 16 + ln] = f2b(acc[mt][nt][r] + bv[nt]);
      wait_lds();  // cross-lane LDS RAW
#pragma unroll
      for (int it = 0; it < 2; ++it) {
        int cid = it * 64 + lane;
        int row = cid >> 3, ch = cid & 7;
        uint4 v = *(const uint4*)&patch[row * 136 + ch * 8];
        *(uint4*)&((u16*)Cv)[(m0 + wm * 128 + mt * 16 + row) * (long)N + n0 + wn * 64 + ch * 8] = v;
      }
      wait_lds();  // patch reads retired before next mt overwrites
    }
  }
}

// ---------------- fused attention per (n, head) ----------------
// qkv row layout [1536]: head h cols [h*192, +192) = q|k|v of 64.
// Block = 4 waves; wave w, strip s handles q-rows [w*64+s*32, +32).
// LDS: Ks [256][64] + Vt [64][256] = 64 KB; P aliases Ks during PV (waves
// are locksteppped by __syncthreads; K re-staged between strips).
__global__ __launch_bounds__(256, 2) void attn_fused(const u16* __restrict__ qkv,
                                                     u16* __restrict__ out) {
  __shared__ alignas(16) u16 Ks[256 * 64];  // [j][64], 16B chunk c stored at c^(j&7)
  __shared__ alignas(16) u16 Vt[64 * 256];  // [d][256], chunk cj stored at cj^(((d>>3)^d)&7)
  const int h = blockIdx.x;
  const long n = blockIdx.y;
  const int tid = threadIdx.x;
  const int lane = tid & 63, wave = tid >> 6;
  const int quad = lane >> 4, ln = lane & 15;
  const u16* base = qkv + (n * 256) * 1536 + h * 192;

  // ---- stage K (coalesced 16B loads; swizzled 16B LDS writes, conflict-free) ----
  auto stageK = [&]() {
    int c = tid & 7, jb = tid >> 3;
#pragma unroll
    for (int rr = 0; rr < 8; ++rr) {
      int j = jb + rr * 32;
      uint4 v = *(const uint4*)(base + (long)j * 1536 + 64 + c * 8);
      *(uint4*)&Ks[j * 64 + ((c ^ (j & 7)) * 8)] = v;
    }
  };
  stageK();
  // ---- stage V^T (coalesced loads; scalar scatter, key=(p^i) -> conflict-free) ----
  {
    int p = tid & 7, jb = tid >> 3;
#pragma unroll
    for (int rr = 0; rr < 8; ++rr) {
      int j = jb + rr * 32;
      union { uint4 v; u16 e[8]; } u;
      u.v = *(const uint4*)(base + (long)j * 1536 + 128 + p * 8);
      int cj = j >> 3, jl = j & 7;
#pragma unroll
      for (int i = 0; i < 8; ++i) {
        int d = p * 8 + i;
        int key = (p ^ i) & 7;  // == ((d>>3)^d)&7
        Vt[d * 256 + ((cj ^ key) * 8) + jl] = u.e[i];
      }
    }
  }
  __syncthreads();

  u16* Pw = &Ks[wave * 2176];  // [16][136] u16, aliases Ks during PV phases
  f32x4 zero = {0.f, 0.f, 0.f, 0.f};

  for (int s = 0; s < 2; ++s) {
    const int row0 = wave * 64 + s * 32;
    // q A-frags from global (rows x 64B lines, read once — coalesced)
    bf16x8 qa[2][2];
#pragma unroll
    for (int mt = 0; mt < 2; ++mt)
#pragma unroll
      for (int kc = 0; kc < 2; ++kc)
        qa[mt][kc] = ld_frag(base + (long)(row0 + mt * 16 + ln) * 1536 + kc * 32 + quad * 8);

    f32x4 sacc[2][16];
#pragma unroll
    for (int mt = 0; mt < 2; ++mt)
#pragma unroll
      for (int jt = 0; jt < 16; ++jt) sacc[mt][jt] = zero;

    // S = q k^T, kb from swizzled LDS
#pragma unroll
    for (int jt = 0; jt < 16; ++jt) {
#pragma unroll
      for (int kc = 0; kc < 2; ++kc) {
        bf16x8 kb = ld_frag(&Ks[(jt * 16 + ln) * 64 + (((kc * 4 + quad) ^ (ln & 7)) * 8)]);
        sacc[0][jt] = __builtin_amdgcn_mfma_f32_16x16x32_bf16(qa[0][kc], kb, sacc[0][jt], 0, 0, 0);
        sacc[1][jt] = __builtin_amdgcn_mfma_f32_16x16x32_bf16(qa[1][kc], kb, sacc[1][jt], 0, 0, 0);
      }
    }
    __syncthreads();  // all waves done reading Ks -> P may alias it

#pragma unroll
    for (int mt = 0; mt < 2; ++mt) {
      // softmax over j (rows at quad*4+r, cols at jt*16+ln)
      float linv[4];
#pragma unroll
      for (int r = 0; r < 4; ++r) {
        float mx = -3.0e38f;
#pragma unroll
        for (int jt = 0; jt < 16; ++jt) mx = fmaxf(mx, sacc[mt][jt][r]);
        mx = fmaxf(mx, __shfl_xor(mx, 1));
        mx = fmaxf(mx, __shfl_xor(mx, 2));
        mx = fmaxf(mx, __shfl_xor(mx, 4));
        mx = fmaxf(mx, __shfl_xor(mx, 8));
        float l = 0.f;
#pragma unroll
        for (int jt = 0; jt < 16; ++jt) {
          float p = __expf((sacc[mt][jt][r] - mx) * 0.125f);  // 1/sqrt(dh)
          sacc[mt][jt][r] = p;
          l += p;
        }
        l += __shfl_xor(l, 1);
        l += __shfl_xor(l, 2);
        l += __shfl_xor(l, 4);
        l += __shfl_xor(l, 8);
        linv[r] = 1.0f / l;
      }

      // O = P V in two j-halves of 128 (P buffer reused; oacc accumulates)
      f32x4 oacc[4];
#pragma unroll
      for (int dt = 0; dt < 4; ++dt) oacc[dt] = zero;
#pragma unroll
      for (int jh = 0; jh < 2; ++jh) {
#pragma unroll
        for (int jl = 0; jl < 8; ++jl) {
          int jt = jh * 8 + jl;
#pragma unroll
          for (int r = 0; r < 4; ++r)
            Pw[(quad * 4 + r) * 136 + jl * 16 + ln] = f2b(sacc[mt][jt][r]);
        }
        wait_lds();  // cross-lane LDS RAW
#pragma unroll
        for (int jcl = 0; jcl < 4; ++jcl) {
          bf16x8 pa = ld_frag(&Pw[ln * 136 + jcl * 32 + quad * 8]);
          int cjb = (jh * 4 + jcl) * 4 + quad;
#pragma unroll
          for (int dt = 0; dt < 4; ++dt) {
            int d = dt * 16 + ln;
            int key = ((d >> 3) ^ d) & 7;
            bf16x8 vb = ld_frag(&Vt[d * 256 + ((cjb ^ key) * 8)]);
            oacc[dt] = __builtin_amdgcn_mfma_f32_16x16x32_bf16(pa, vb, oacc[dt], 0, 0, 0);
          }
        }
      }
      // stage O tile (16 x 64) into Pw, then coalesced 16B global stores
#pragma unroll
      for (int dt = 0; dt < 4; ++dt)
#pragma unroll
        for (int r = 0; r < 4; ++r)
          Pw[(quad * 4 + r) * 136 + dt * 16 + ln] = f2b(oacc[dt][r] * linv[r]);
      wait_lds();
#pragma unroll
      for (int it = 0; it < 2; ++it) {
        int cid = it * 64 + lane;
        int row = cid >> 3, ch = cid & 7;
        uint4 v = *(const uint4*)&Pw[row * 136 + ch * 8];
        *(uint4*)&out[(n * 256 + row0 + mt * 16 + row) * 512 + h * 64 + ch * 8] = v;
      }
    }
    __syncthreads();  // P region quiesced
    if (s == 0) {
      stageK();       // restore K for strip 1
      __syncthreads();
    }
  }
}

extern "C" void kernel_launch(void* const* d_in, const int* in_sizes, int n_in,
                              void* d_out, int out_size, void* d_ws, size_t ws_size,
                              hipStream_t stream) {
  const float* x      = (const float*)d_in[0];  // [65536][512] fp32
  const float* w_qkv  = (const float*)d_in[1];  // [512][1536]
  const float* b_qkv  = (const float*)d_in[2];  // [1536]
  const float* w_proj = (const float*)d_in[3];  // [512][512]
  const float* b_proj = (const float*)d_in[4];  // [512]
  float* out = (float*)d_out;                   // [65536][512] fp32

  char* ws = (char*)d_ws;
  u16* xb   = (u16*)ws;                                         // 64 MiB
  u16* qkv  = (u16*)(ws + 67108864L);                           // 192 MiB
  u16* attn = (u16*)(ws + 67108864L + 201326592L);              // 64 MiB
  u16* Wt1  = (u16*)(ws + 67108864L + 201326592L + 67108864L);  // 1536x512
  u16* Wt2  = Wt1 + 1536 * 512;                                 // 512x512

  convert_f32_bf16<<<16384, 256, 0, stream>>>(x, xb);
  transpose_w<<<dim3(24, 8), 256, 0, stream>>>(w_qkv, Wt1, 512, 1536);
  transpose_w<<<dim3(8, 8), 256, 0, stream>>>(w_proj, Wt2, 512, 512);
  // grids: (M/256)*(N/128) blocks, both % 8 == 0 (bijective XCD swizzle)
  gemm_pipe<false><<<dim3(12 * 256), 256, 0, stream>>>(xb, Wt1, b_qkv, qkv, 65536, 1536, 512);
  attn_fused<<<dim3(8, 256), 256, 0, stream>>>(qkv, attn);
  gemm_pipe<true><<<dim3(4 * 256), 256, 0, stream>>>(attn, Wt2, b_proj, out, 65536, 512, 512);
}

// Round 4
// 566.585 us; speedup vs baseline: 1.0469x; 1.0469x over previous
//
#include <hip/hip_runtime.h>

typedef unsigned short u16;
typedef unsigned int u32;
typedef __bf16 bf16x8 __attribute__((ext_vector_type(8)));
typedef float f32x4 __attribute__((ext_vector_type(4)));

__device__ __forceinline__ u16 f2b(float f) {
  u32 u = __builtin_bit_cast(u32, f);
  u32 r = (u + 0x7fffu + ((u >> 16) & 1u)) >> 16;  // RNE
  return (u16)r;
}
__device__ __forceinline__ bf16x8 ld_frag(const u16* p) {
  uint4 v = *(const uint4*)p;
  return __builtin_bit_cast(bf16x8, v);
}
__device__ __forceinline__ void async_lds16(const u16* g, u16* lds) {
  __builtin_amdgcn_global_load_lds(
      (const __attribute__((address_space(1))) void*)g,
      (__attribute__((address_space(3))) void*)lds, 16, 0, 0);
}
// wait lgkmcnt(0) only (vmcnt=63, expcnt=7 untouched)
__device__ __forceinline__ void wait_lds() { __builtin_amdgcn_s_waitcnt(0xc07f); }

// ---------------- fp32 -> bf16 bulk convert (x) ----------------
__global__ __launch_bounds__(256) void convert_f32_bf16(const float* __restrict__ in,
                                                        u16* __restrict__ out) {
  long i = ((long)blockIdx.x * 256 + threadIdx.x) * 8;
  float4 a = *(const float4*)(in + i);
  float4 b = *(const float4*)(in + i + 4);
  union { uint4 v; u16 e[8]; } u;
  u.e[0] = f2b(a.x); u.e[1] = f2b(a.y); u.e[2] = f2b(a.z); u.e[3] = f2b(a.w);
  u.e[4] = f2b(b.x); u.e[5] = f2b(b.y); u.e[6] = f2b(b.z); u.e[7] = f2b(b.w);
  *(uint4*)(out + i) = u.v;
}

// ---------------- weight transpose+convert: W_f32[K][N] -> Wt_bf16[N][K] ----------------
__global__ __launch_bounds__(256) void transpose_w(const float* __restrict__ W,
                                                   u16* __restrict__ Wt,
                                                   int K, int N) {
  __shared__ alignas(16) u16 T[64][80];
  const int n0 = blockIdx.x * 64, k0 = blockIdx.y * 64;
  const int t = threadIdx.x;
  {
    int kk = t >> 3, c = t & 7;
#pragma unroll
    for (int rr = 0; rr < 2; ++rr) {
      int kr = kk + rr * 32;
      const float* src = W + (long)(k0 + kr) * N + n0 + c * 8;
      float4 a = *(const float4*)src;
      float4 b = *(const float4*)(src + 4);
      u16* dst = &T[kr][c * 8];
      dst[0] = f2b(a.x); dst[1] = f2b(a.y); dst[2] = f2b(a.z); dst[3] = f2b(a.w);
      dst[4] = f2b(b.x); dst[5] = f2b(b.y); dst[6] = f2b(b.z); dst[7] = f2b(b.w);
    }
  }
  __syncthreads();
  {
    int nn = t >> 3, kc = t & 7;
#pragma unroll
    for (int rr = 0; rr < 2; ++rr) {
      int nr = nn + rr * 32;
      union { uint4 v; u16 e[8]; } u;
#pragma unroll
      for (int i = 0; i < 8; ++i) u.e[i] = T[kc * 8 + i][nr];
      *(uint4*)(Wt + (long)(n0 + nr) * K + k0 + kc * 8) = u.v;
    }
  }
}

// ---------------- pipelined GEMM: C[M][N] = A_bf16[M][K] * Bt_bf16[N][K]^T + bias ----------------
// BM=256 BN=256 BK=32; 512 thr = 8 waves (2M x 4N), per-wave 128x64 (acc[8][4]).
// LDS ring of 3 K-tile slots (32 KiB each = 96 KiB) -> 1 block/CU, 2 waves/SIMD;
// __launch_bounds__(512,2) caps total regs at 256/wave (acc 128 -> AGPR side of
// the unified file; ~110 VGPR live side, no spill).
// ONE barrier per K-tile; within a tile: 4 quadrant phases ordered to minimize
// fragment liveness (Alo*Bl, Ahi*Bl, Alo*Bh, Ahi*Bh) with JIT ds_reads, each
// separated by 1 global_load_lds stage unit of tile t+2, MFMAs under setprio.
// Counted vmcnt(4) gate at tile end (never 0 mid-loop): own t+2 stages may fly,
// own t+1 stages retired; barrier => ALL waves' t+1 loads landed.
// Tail: at t=KT-2 use vmcnt(0) (only 4 outstanding; tile KT-1 must be resident).
// Race-freedom (ring-3): slot t%3 fully read before barrier(end t) [every
// ds_read feeds an MFMA before the barrier]; next write to that slot is tile
// t+3's staging, issued during tile t+1 -- strictly after that barrier.
// Swizzle (64B rows, 4x16B chunks): logical chunk c at position c ^ ((row>>1)&3);
// staged with linear LDS dest + inverse-swizzled global source (chunk
// (L&3)^((L>>3)&3)); reads use the matching XOR. Read bank pattern == linear
// stride-16B (2 lanes/bank) = minimum for wave64.
template <bool OUT_F32>
__global__ __launch_bounds__(512, 2) void gemm_pipe(const u16* __restrict__ A,
                                                    const u16* __restrict__ Bt,
                                                    const float* __restrict__ bias,
                                                    void* __restrict__ Cv,
                                                    int M, int N, int K) {
  __shared__ alignas(16) u16 lds[3 * 16384];  // slot: A [256][32] @0, B [256][32] @8192
  const int tid = threadIdx.x;
  const int lane = tid & 63, wave = tid >> 6;
  const int quad = lane >> 4, ln = lane & 15;
  const int wm = wave >> 2, wn = wave & 3;  // per-wave 128x64 tile

  // XCD-aware bijective swizzle (nwg % 8 == 0 for both launches)
  const int nwg = gridDim.x;
  const int bid = blockIdx.x;
  const int wg = (bid & 7) * (nwg >> 3) + (bid >> 3);
  const int ntn = N >> 8;
  const int tn = wg % ntn, tm = wg / ntn;
  const long m0 = (long)tm * 256;
  const long n0 = (long)tn * 256;

  // staging: one source-level global_load_lds = 8 waves x 1KB = 8KB = 128 rows x 64B.
  // wave w, lane L covers row u*128 + w*16 + (L>>2), chunk position L&3 holding
  // global chunk (L&3)^((L>>3)&3)  [inverse of read swizzle key (row>>1)&3].
  const int srow = wave * 16 + (lane >> 2);
  const int gsw = ((lane & 3) ^ ((lane >> 3) & 3)) * 8;
  const u16* gA[2];
  const u16* gB[2];
#pragma unroll
  for (int u = 0; u < 2; ++u) gA[u] = A + (long)(m0 + u * 128 + srow) * K + gsw;
#pragma unroll
  for (int u = 0; u < 2; ++u) gB[u] = Bt + (long)(n0 + u * 128 + srow) * K + gsw;

  const int KT = K >> 5;

  auto stageA = [&](int t, int u) {
    u16* s = &lds[(t % 3) * 16384 + u * 4096 + wave * 512];
    async_lds16(gA[u] + (long)t * 32, s);
  };
  auto stageB = [&](int t, int u) {
    u16* s = &lds[(t % 3) * 16384 + 8192 + u * 4096 + wave * 512];
    async_lds16(gB[u] + (long)t * 32, s);
  };

  const int cpos = (quad ^ ((ln >> 1) & 3)) * 8;  // read-side swizzled chunk (elems)
  auto ldA = [&](int t, int mt) {
    int row = wm * 128 + mt * 16 + ln;
    return ld_frag(&lds[(t % 3) * 16384 + row * 32 + cpos]);
  };
  auto ldB = [&](int t, int nt) {
    int row = wn * 64 + nt * 16 + ln;
    return ld_frag(&lds[(t % 3) * 16384 + 8192 + row * 32 + cpos]);
  };

  f32x4 zero = {0.f, 0.f, 0.f, 0.f};
  f32x4 acc[8][4];
#pragma unroll
  for (int i = 0; i < 8; ++i)
#pragma unroll
    for (int j = 0; j < 4; ++j) acc[i][j] = zero;

  // prologue: stage tiles 0,1 (4 units each); wait tile 0 landed (tile 1 flies)
  stageA(0, 0); stageA(0, 1); stageB(0, 0); stageB(0, 1);
  stageA(1, 0); stageA(1, 1); stageB(1, 0); stageB(1, 1);
  __builtin_amdgcn_s_waitcnt(0x0f74);  // vmcnt(4)
  __builtin_amdgcn_s_barrier();

  for (int t = 0; t < KT; ++t) {
    bf16x8 Alo[4], Ahi[4], Bl[2], Bh[2];
#pragma unroll
    for (int mt = 0; mt < 4; ++mt) Alo[mt] = ldA(t, mt);
    Bl[0] = ldB(t, 0); Bl[1] = ldB(t, 1);
    if (t + 2 < KT) stageA(t + 2, 0);
    // Q0: m-lo x n-lo
    __builtin_amdgcn_s_setprio(1);
#pragma unroll
    for (int mt = 0; mt < 4; ++mt)
#pragma unroll
      for (int nt = 0; nt < 2; ++nt)
        acc[mt][nt] = __builtin_amdgcn_mfma_f32_16x16x32_bf16(Alo[mt], Bl[nt], acc[mt][nt], 0, 0, 0);
    __builtin_amdgcn_s_setprio(0);
#pragma unroll
    for (int mt = 0; mt < 4; ++mt) Ahi[mt] = ldA(t, mt + 4);
    if (t + 2 < KT) stageA(t + 2, 1);
    // Q1: m-hi x n-lo (Bl dies after this)
    __builtin_amdgcn_s_setprio(1);
#pragma unroll
    for (int mt = 0; mt < 4; ++mt)
#pragma unroll
      for (int nt = 0; nt < 2; ++nt)
        acc[mt + 4][nt] = __builtin_amdgcn_mfma_f32_16x16x32_bf16(Ahi[mt], Bl[nt], acc[mt + 4][nt], 0, 0, 0);
    __builtin_amdgcn_s_setprio(0);
    Bh[0] = ldB(t, 2); Bh[1] = ldB(t, 3);
    if (t + 2 < KT) stageB(t + 2, 0);
    // Q2: m-lo x n-hi (Alo dies after this)
    __builtin_amdgcn_s_setprio(1);
#pragma unroll
    for (int mt = 0; mt < 4; ++mt)
#pragma unroll
      for (int nt = 0; nt < 2; ++nt)
        acc[mt][nt + 2] = __builtin_amdgcn_mfma_f32_16x16x32_bf16(Alo[mt], Bh[nt], acc[mt][nt + 2], 0, 0, 0);
    __builtin_amdgcn_s_setprio(0);
    if (t + 2 < KT) stageB(t + 2, 1);
    // Q3: m-hi x n-hi
    __builtin_amdgcn_s_setprio(1);
#pragma unroll
    for (int mt = 0; mt < 4; ++mt)
#pragma unroll
      for (int nt = 0; nt < 2; ++nt)
        acc[mt + 4][nt + 2] = __builtin_amdgcn_mfma_f32_16x16x32_bf16(Ahi[mt], Bh[nt], acc[mt + 4][nt + 2], 0, 0, 0);
    __builtin_amdgcn_s_setprio(0);
    if (t + 2 < KT)      __builtin_amdgcn_s_waitcnt(0x0f74);  // vmcnt(4): own t+1 retired
    else if (t + 1 < KT) __builtin_amdgcn_s_waitcnt(0x0f70);  // vmcnt(0): tail drain
    __builtin_amdgcn_s_barrier();
  }

  __syncthreads();  // quiesce before LDS reuse by epilogue

  if (OUT_F32) {
#pragma unroll
    for (int nt = 0; nt < 4; ++nt) {
      long coln = n0 + wn * 64 + nt * 16 + ln;
      float bv = bias[coln];
#pragma unroll
      for (int mt = 0; mt < 8; ++mt) {
        long rowb = m0 + wm * 128 + mt * 16 + quad * 4;
#pragma unroll
        for (int r = 0; r < 4; ++r)
          ((float*)Cv)[(rowb + r) * N + coln] = acc[mt][nt][r] + bv;
      }
    }
  } else {
    // bf16: wave-private LDS patch for full-line 16B stores
    u16* patch = &lds[wave * 2176];  // [16][136]
    float bv[4];
#pragma unroll
    for (int nt = 0; nt < 4; ++nt) bv[nt] = bias[n0 + wn * 64 + nt * 16 + ln];
#pragma unroll
    for (int mt = 0; mt < 8; ++mt) {
#pragma unroll
      for (int nt = 0; nt < 4; ++nt)
#pragma unroll
        for (int r = 0; r < 4; ++r)
          patch[(quad * 4 + r) * 136 + nt * 16 + ln] = f2b(acc[mt][nt][r] + bv[nt]);
      wait_lds();  // cross-lane LDS RAW
#pragma unroll
      for (int it = 0; it < 2; ++it) {
        int cid = it * 64 + lane;
        int row = cid >> 3, ch = cid & 7;
        uint4 v = *(const uint4*)&patch[row * 136 + ch * 8];
        *(uint4*)&((u16*)Cv)[(m0 + wm * 128 + mt * 16 + row) * (long)N + n0 + wn * 64 + ch * 8] = v;
      }
      wait_lds();  // patch reads retired before next mt overwrites
    }
  }
}

// ---------------- fused attention per (n, head) ----------------
// qkv row layout [1536]: head h cols [h*192, +192) = q|k|v of 64.
// Block = 4 waves; wave w, strip s handles q-rows [w*64+s*32, +32).
// LDS: Ks [256][64] + Vt [64][256] = 64 KB; P aliases Ks during PV (waves
// are locksteppped by __syncthreads; K re-staged between strips).
__global__ __launch_bounds__(256, 2) void attn_fused(const u16* __restrict__ qkv,
                                                     u16* __restrict__ out) {
  __shared__ alignas(16) u16 Ks[256 * 64];  // [j][64], 16B chunk c stored at c^(j&7)
  __shared__ alignas(16) u16 Vt[64 * 256];  // [d][256], chunk cj stored at cj^(((d>>3)^d)&7)
  const int h = blockIdx.x;
  const long n = blockIdx.y;
  const int tid = threadIdx.x;
  const int lane = tid & 63, wave = tid >> 6;
  const int quad = lane >> 4, ln = lane & 15;
  const u16* base = qkv + (n * 256) * 1536 + h * 192;

  // ---- stage K (coalesced 16B loads; swizzled 16B LDS writes, conflict-free) ----
  auto stageK = [&]() {
    int c = tid & 7, jb = tid >> 3;
#pragma unroll
    for (int rr = 0; rr < 8; ++rr) {
      int j = jb + rr * 32;
      uint4 v = *(const uint4*)(base + (long)j * 1536 + 64 + c * 8);
      *(uint4*)&Ks[j * 64 + ((c ^ (j & 7)) * 8)] = v;
    }
  };
  stageK();
  // ---- stage V^T (coalesced loads; scalar scatter, key=(p^i) -> conflict-free) ----
  {
    int p = tid & 7, jb = tid >> 3;
#pragma unroll
    for (int rr = 0; rr < 8; ++rr) {
      int j = jb + rr * 32;
      union { uint4 v; u16 e[8]; } u;
      u.v = *(const uint4*)(base + (long)j * 1536 + 128 + p * 8);
      int cj = j >> 3, jl = j & 7;
#pragma unroll
      for (int i = 0; i < 8; ++i) {
        int d = p * 8 + i;
        int key = (p ^ i) & 7;  // == ((d>>3)^d)&7
        Vt[d * 256 + ((cj ^ key) * 8) + jl] = u.e[i];
      }
    }
  }
  __syncthreads();

  u16* Pw = &Ks[wave * 2176];  // [16][136] u16, aliases Ks during PV phases
  f32x4 zero = {0.f, 0.f, 0.f, 0.f};

  for (int s = 0; s < 2; ++s) {
    const int row0 = wave * 64 + s * 32;
    // q A-frags from global (rows x 64B lines, read once — coalesced)
    bf16x8 qa[2][2];
#pragma unroll
    for (int mt = 0; mt < 2; ++mt)
#pragma unroll
      for (int kc = 0; kc < 2; ++kc)
        qa[mt][kc] = ld_frag(base + (long)(row0 + mt * 16 + ln) * 1536 + kc * 32 + quad * 8);

    f32x4 sacc[2][16];
#pragma unroll
    for (int mt = 0; mt < 2; ++mt)
#pragma unroll
      for (int jt = 0; jt < 16; ++jt) sacc[mt][jt] = zero;

    // S = q k^T, kb from swizzled LDS
#pragma unroll
    for (int jt = 0; jt < 16; ++jt) {
#pragma unroll
      for (int kc = 0; kc < 2; ++kc) {
        bf16x8 kb = ld_frag(&Ks[(jt * 16 + ln) * 64 + (((kc * 4 + quad) ^ (ln & 7)) * 8)]);
        sacc[0][jt] = __builtin_amdgcn_mfma_f32_16x16x32_bf16(qa[0][kc], kb, sacc[0][jt], 0, 0, 0);
        sacc[1][jt] = __builtin_amdgcn_mfma_f32_16x16x32_bf16(qa[1][kc], kb, sacc[1][jt], 0, 0, 0);
      }
    }
    __syncthreads();  // all waves done reading Ks -> P may alias it

#pragma unroll
    for (int mt = 0; mt < 2; ++mt) {
      // softmax over j (rows at quad*4+r, cols at jt*16+ln)
      float linv[4];
#pragma unroll
      for (int r = 0; r < 4; ++r) {
        float mx = -3.0e38f;
#pragma unroll
        for (int jt = 0; jt < 16; ++jt) mx = fmaxf(mx, sacc[mt][jt][r]);
        mx = fmaxf(mx, __shfl_xor(mx, 1));
        mx = fmaxf(mx, __shfl_xor(mx, 2));
        mx = fmaxf(mx, __shfl_xor(mx, 4));
        mx = fmaxf(mx, __shfl_xor(mx, 8));
        float l = 0.f;
#pragma unroll
        for (int jt = 0; jt < 16; ++jt) {
          float p = __expf((sacc[mt][jt][r] - mx) * 0.125f);  // 1/sqrt(dh)
          sacc[mt][jt][r] = p;
          l += p;
        }
        l += __shfl_xor(l, 1);
        l += __shfl_xor(l, 2);
        l += __shfl_xor(l, 4);
        l += __shfl_xor(l, 8);
        linv[r] = 1.0f / l;
      }

      // O = P V in two j-halves of 128 (P buffer reused; oacc accumulates)
      f32x4 oacc[4];
#pragma unroll
      for (int dt = 0; dt < 4; ++dt) oacc[dt] = zero;
#pragma unroll
      for (int jh = 0; jh < 2; ++jh) {
#pragma unroll
        for (int jl = 0; jl < 8; ++jl) {
          int jt = jh * 8 + jl;
#pragma unroll
          for (int r = 0; r < 4; ++r)
            Pw[(quad * 4 + r) * 136 + jl * 16 + ln] = f2b(sacc[mt][jt][r]);
        }
        wait_lds();  // cross-lane LDS RAW
#pragma unroll
        for (int jcl = 0; jcl < 4; ++jcl) {
          bf16x8 pa = ld_frag(&Pw[ln * 136 + jcl * 32 + quad * 8]);
          int cjb = (jh * 4 + jcl) * 4 + quad;
#pragma unroll
          for (int dt = 0; dt < 4; ++dt) {
            int d = dt * 16 + ln;
            int key = ((d >> 3) ^ d) & 7;
            bf16x8 vb = ld_frag(&Vt[d * 256 + ((cjb ^ key) * 8)]);
            oacc[dt] = __builtin_amdgcn_mfma_f32_16x16x32_bf16(pa, vb, oacc[dt], 0, 0, 0);
          }
        }
      }
      // stage O tile (16 x 64) into Pw, then coalesced 16B global stores
#pragma unroll
      for (int dt = 0; dt < 4; ++dt)
#pragma unroll
        for (int r = 0; r < 4; ++r)
          Pw[(quad * 4 + r) * 136 + dt * 16 + ln] = f2b(oacc[dt][r] * linv[r]);
      wait_lds();
#pragma unroll
      for (int it = 0; it < 2; ++it) {
        int cid = it * 64 + lane;
        int row = cid >> 3, ch = cid & 7;
        uint4 v = *(const uint4*)&Pw[row * 136 + ch * 8];
        *(uint4*)&out[(n * 256 + row0 + mt * 16 + row) * 512 + h * 64 + ch * 8] = v;
      }
    }
    __syncthreads();  // P region quiesced
    if (s == 0) {
      stageK();       // restore K for strip 1
      __syncthreads();
    }
  }
}

extern "C" void kernel_launch(void* const* d_in, const int* in_sizes, int n_in,
                              void* d_out, int out_size, void* d_ws, size_t ws_size,
                              hipStream_t stream) {
  const float* x      = (const float*)d_in[0];  // [65536][512] fp32
  const float* w_qkv  = (const float*)d_in[1];  // [512][1536]
  const float* b_qkv  = (const float*)d_in[2];  // [1536]
  const float* w_proj = (const float*)d_in[3];  // [512][512]
  const float* b_proj = (const float*)d_in[4];  // [512]
  float* out = (float*)d_out;                   // [65536][512] fp32

  char* ws = (char*)d_ws;
  u16* xb   = (u16*)ws;                                         // 64 MiB
  u16* qkv  = (u16*)(ws + 67108864L);                           // 192 MiB
  u16* attn = (u16*)(ws + 67108864L + 201326592L);              // 64 MiB
  u16* Wt1  = (u16*)(ws + 67108864L + 201326592L + 67108864L);  // 1536x512
  u16* Wt2  = Wt1 + 1536 * 512;                                 // 512x512

  convert_f32_bf16<<<16384, 256, 0, stream>>>(x, xb);
  transpose_w<<<dim3(24, 8), 256, 0, stream>>>(w_qkv, Wt1, 512, 1536);
  transpose_w<<<dim3(8, 8), 256, 0, stream>>>(w_proj, Wt2, 512, 512);
  // grids: (M/256)*(N/256) blocks, both % 8 == 0 (bijective XCD swizzle)
  gemm_pipe<false><<<dim3(6 * 256), 512, 0, stream>>>(xb, Wt1, b_qkv, qkv, 65536, 1536, 512);
  attn_fused<<<dim3(8, 256), 256, 0, stream>>>(qkv, attn);
  gemm_pipe<true><<<dim3(2 * 256), 512, 0, stream>>>(attn, Wt2, b_proj, out, 65536, 512, 512);
}

// Round 5
// 552.697 us; speedup vs baseline: 1.0732x; 1.0251x over previous
//
#include <hip/hip_runtime.h>

typedef unsigned short u16;
typedef unsigned int u32;
typedef __bf16 bf16x8 __attribute__((ext_vector_type(8)));
typedef float f32x4 __attribute__((ext_vector_type(4)));

__device__ __forceinline__ u16 f2b(float f) {
  u32 u = __builtin_bit_cast(u32, f);
  u32 r = (u + 0x7fffu + ((u >> 16) & 1u)) >> 16;  // RNE
  return (u16)r;
}
__device__ __forceinline__ bf16x8 ld_frag(const u16* p) {
  uint4 v = *(const uint4*)p;
  return __builtin_bit_cast(bf16x8, v);
}
__device__ __forceinline__ void async_lds16(const u16* g, u16* lds) {
  __builtin_amdgcn_global_load_lds(
      (const __attribute__((address_space(1))) void*)g,
      (__attribute__((address_space(3))) void*)lds, 16, 0, 0);
}
// wait lgkmcnt(0) only (vmcnt=63, expcnt=7 untouched)
__device__ __forceinline__ void wait_lds() { __builtin_amdgcn_s_waitcnt(0xc07f); }

// ---------------- fp32 -> bf16 bulk convert (x) ----------------
__global__ __launch_bounds__(256) void convert_f32_bf16(const float* __restrict__ in,
                                                        u16* __restrict__ out) {
  long i = ((long)blockIdx.x * 256 + threadIdx.x) * 8;
  float4 a = *(const float4*)(in + i);
  float4 b = *(const float4*)(in + i + 4);
  union { uint4 v; u16 e[8]; } u;
  u.e[0] = f2b(a.x); u.e[1] = f2b(a.y); u.e[2] = f2b(a.z); u.e[3] = f2b(a.w);
  u.e[4] = f2b(b.x); u.e[5] = f2b(b.y); u.e[6] = f2b(b.z); u.e[7] = f2b(b.w);
  *(uint4*)(out + i) = u.v;
}

// ---------------- weight transpose+convert: W_f32[K][N] -> Wt_bf16[N][K] ----------------
__global__ __launch_bounds__(256) void transpose_w(const float* __restrict__ W,
                                                   u16* __restrict__ Wt,
                                                   int K, int N) {
  __shared__ alignas(16) u16 T[64][80];
  const int n0 = blockIdx.x * 64, k0 = blockIdx.y * 64;
  const int t = threadIdx.x;
  {
    int kk = t >> 3, c = t & 7;
#pragma unroll
    for (int rr = 0; rr < 2; ++rr) {
      int kr = kk + rr * 32;
      const float* src = W + (long)(k0 + kr) * N + n0 + c * 8;
      float4 a = *(const float4*)src;
      float4 b = *(const float4*)(src + 4);
      u16* dst = &T[kr][c * 8];
      dst[0] = f2b(a.x); dst[1] = f2b(a.y); dst[2] = f2b(a.z); dst[3] = f2b(a.w);
      dst[4] = f2b(b.x); dst[5] = f2b(b.y); dst[6] = f2b(b.z); dst[7] = f2b(b.w);
    }
  }
  __syncthreads();
  {
    int nn = t >> 3, kc = t & 7;
#pragma unroll
    for (int rr = 0; rr < 2; ++rr) {
      int nr = nn + rr * 32;
      union { uint4 v; u16 e[8]; } u;
#pragma unroll
      for (int i = 0; i < 8; ++i) u.e[i] = T[kc * 8 + i][nr];
      *(uint4*)(Wt + (long)(n0 + nr) * K + k0 + kc * 8) = u.v;
    }
  }
}

// ---------------- phased GEMM (m201-style): C = A_bf16[M][K] * Bt_bf16[N][K]^T + bias ----------
// BM=BN=256, BK=64; 512 thr = 8 waves (2M x 4N), wave tile 128x64, acc[8][4].
// LDS: double-buffered K-tile slots, 64 KiB each (A [256][64] + B [256][64]) = 128 KiB.
// Per K-tile: {vmcnt(0) gate + barrier} then 4 PHASES, each:
//   {<=12 ds_read_b128 | stage one 16KB half-tile of t+1 (2 gload_lds) | barrier |
//    lgkmcnt(0) | setprio(1) 16 MFMA setprio(0) | barrier}
// Phase reads (wave wm,wn): ph0 A[mt0-3]x2ks + B[nt0-1]x2ks; ph1 B[nt2-3]; ph2 A[mt4-7];
// ph3 none (b0 frags held in regs since ph0). MFMA quadrants: (lo,lo)(lo,hi)(hi,hi)(hi,lo).
// Stage order A0,A1,B0,B1 -> each target region's last LDS reader finished >=2 barriers
// earlier (A halves read in ph0/ph2, B halves in ph0/ph1 of the PREVIOUS tile).
// Gate slack: oldest in-flight load at the gate was issued 4 phases (~2800 cyc) earlier,
// newest (B1) 2 phases (~1400 cyc) -> vmcnt(0) drain is nominal, loads otherwise stay
// in flight across all intra-tile barriers (counted-vmcnt principle).
// Swizzle (128B rows, 8x16B chunks): chunk c stored at position c^(row&7); staged with
// linear LDS dest + inverse-swizzled global source (chunk (tid&7)^((tid>>3)&7));
// reads use the matching XOR -> uniform 8 dwords/bank per wave access (conflict-free).
template <bool OUT_F32>
__global__ __launch_bounds__(512, 2) void gemm_pipe(const u16* __restrict__ A,
                                                    const u16* __restrict__ Bt,
                                                    const float* __restrict__ bias,
                                                    void* __restrict__ Cv,
                                                    int M, int N, int K) {
  __shared__ alignas(16) u16 lds[2 * 32768];  // slot s: A @ s*32768, B @ s*32768+16384
  const int tid = threadIdx.x;
  const int lane = tid & 63, wave = tid >> 6;
  const int quad = lane >> 4, ln = lane & 15;
  const int wm = wave >> 2, wn = wave & 3;  // per-wave 128x64 tile

  // XCD-aware bijective swizzle (nwg % 8 == 0 for both launches)
  const int nwg = gridDim.x;
  const int bid = blockIdx.x;
  const int wg = (bid & 7) * (nwg >> 3) + (bid >> 3);
  const int ntn = N >> 8;
  const int tn = wg % ntn, tm = wg / ntn;
  const long m0 = (long)tm * 256;
  const long n0 = (long)tn * 256;

  // staging source: thread covers row (tid>>3) of a 64-row unit, holding the
  // inverse-swizzled chunk (tid&7)^((tid>>3)&7). One gload_lds = 512thr x 16B = 64 rows.
  const int strow = tid >> 3;
  const int gsw = ((tid & 7) ^ (strow & 7)) * 8;
  const u16* gA = A + (m0 + strow) * (long)K + gsw;
  const u16* gB = Bt + (n0 + strow) * (long)K + gsw;

  const int KT = K >> 6;

  auto stageA = [&](int t, int h, int i) {  // A half-tile h, instr i: rows h*128+i*64..+64
    u16* d = &lds[(t & 1) * 32768 + (h * 128 + i * 64) * 64 + wave * 512];
    async_lds16(gA + (long)(h * 128 + i * 64) * K + (long)t * 64, d);
  };
  auto stageB = [&](int t, int h, int i) {
    u16* d = &lds[(t & 1) * 32768 + 16384 + (h * 128 + i * 64) * 64 + wave * 512];
    async_lds16(gB + (long)(h * 128 + i * 64) * K + (long)t * 64, d);
  };

  auto ldA = [&](int t, int mt, int ks) {
    int row = wm * 128 + mt * 16 + ln;
    int pos = (ks * 4 + quad) ^ (row & 7);
    return ld_frag(&lds[(t & 1) * 32768 + row * 64 + pos * 8]);
  };
  auto ldB = [&](int t, int nt, int ks) {
    int row = wn * 64 + nt * 16 + ln;
    int pos = (ks * 4 + quad) ^ (row & 7);
    return ld_frag(&lds[(t & 1) * 32768 + 16384 + row * 64 + pos * 8]);
  };

  f32x4 zero = {0.f, 0.f, 0.f, 0.f};
  f32x4 acc[8][4];
#pragma unroll
  for (int i = 0; i < 8; ++i)
#pragma unroll
    for (int j = 0; j < 4; ++j) acc[i][j] = zero;

  // prologue: stage tile 0 fully (8 gload_lds); loop's tile-0 gate waits it
  stageA(0, 0, 0); stageA(0, 0, 1); stageA(0, 1, 0); stageA(0, 1, 1);
  stageB(0, 0, 0); stageB(0, 0, 1); stageB(0, 1, 0); stageB(0, 1, 1);

  for (int t = 0; t < KT; ++t) {
    const bool pf = (t + 1 < KT);
    // ---- tile gate: all waves' tile-t stages landed & visible ----
    __builtin_amdgcn_s_waitcnt(0x0f70);  // vmcnt(0) (oldest issued 2-4 phases ago)
    __builtin_amdgcn_s_barrier();

    bf16x8 a[8], b0[4], b1[4];
    // ---- phase 0: A-lo + B-lo reads; stage A0(t+1); MFMA (m-lo x n-lo) ----
#pragma unroll
    for (int mt = 0; mt < 4; ++mt)
#pragma unroll
      for (int ks = 0; ks < 2; ++ks) a[mt * 2 + ks] = ldA(t, mt, ks);
#pragma unroll
    for (int nt = 0; nt < 2; ++nt)
#pragma unroll
      for (int ks = 0; ks < 2; ++ks) b0[nt * 2 + ks] = ldB(t, nt, ks);
    if (pf) { stageA(t + 1, 0, 0); stageA(t + 1, 0, 1); }
    __builtin_amdgcn_s_barrier();
    wait_lds();
    __builtin_amdgcn_s_setprio(1);
#pragma unroll
    for (int mt = 0; mt < 4; ++mt)
#pragma unroll
      for (int nt = 0; nt < 2; ++nt)
#pragma unroll
        for (int ks = 0; ks < 2; ++ks)
          acc[mt][nt] = __builtin_amdgcn_mfma_f32_16x16x32_bf16(a[mt * 2 + ks], b0[nt * 2 + ks], acc[mt][nt], 0, 0, 0);
    __builtin_amdgcn_s_setprio(0);
    __builtin_amdgcn_s_barrier();
    // ---- phase 1: B-hi reads; stage A1(t+1); MFMA (m-lo x n-hi) ----
#pragma unroll
    for (int nt = 0; nt < 2; ++nt)
#pragma unroll
      for (int ks = 0; ks < 2; ++ks) b1[nt * 2 + ks] = ldB(t, nt + 2, ks);
    if (pf) { stageA(t + 1, 1, 0); stageA(t + 1, 1, 1); }
    __builtin_amdgcn_s_barrier();
    wait_lds();
    __builtin_amdgcn_s_setprio(1);
#pragma unroll
    for (int mt = 0; mt < 4; ++mt)
#pragma unroll
      for (int nt = 0; nt < 2; ++nt)
#pragma unroll
        for (int ks = 0; ks < 2; ++ks)
          acc[mt][nt + 2] = __builtin_amdgcn_mfma_f32_16x16x32_bf16(a[mt * 2 + ks], b1[nt * 2 + ks], acc[mt][nt + 2], 0, 0, 0);
    __builtin_amdgcn_s_setprio(0);
    __builtin_amdgcn_s_barrier();
    // ---- phase 2: A-hi reads; stage B0(t+1); MFMA (m-hi x n-hi) ----
#pragma unroll
    for (int mt = 0; mt < 4; ++mt)
#pragma unroll
      for (int ks = 0; ks < 2; ++ks) a[mt * 2 + ks] = ldA(t, mt + 4, ks);
    if (pf) { stageB(t + 1, 0, 0); stageB(t + 1, 0, 1); }
    __builtin_amdgcn_s_barrier();
    wait_lds();
    __builtin_amdgcn_s_setprio(1);
#pragma unroll
    for (int mt = 0; mt < 4; ++mt)
#pragma unroll
      for (int nt = 0; nt < 2; ++nt)
#pragma unroll
        for (int ks = 0; ks < 2; ++ks)
          acc[mt + 4][nt + 2] = __builtin_amdgcn_mfma_f32_16x16x32_bf16(a[mt * 2 + ks], b1[nt * 2 + ks], acc[mt + 4][nt + 2], 0, 0, 0);
    __builtin_amdgcn_s_setprio(0);
    __builtin_amdgcn_s_barrier();
    // ---- phase 3: no reads; stage B1(t+1); MFMA (m-hi x n-lo, b0 held) ----
    if (pf) { stageB(t + 1, 1, 0); stageB(t + 1, 1, 1); }
    __builtin_amdgcn_s_barrier();
    __builtin_amdgcn_s_setprio(1);
#pragma unroll
    for (int mt = 0; mt < 4; ++mt)
#pragma unroll
      for (int nt = 0; nt < 2; ++nt)
#pragma unroll
        for (int ks = 0; ks < 2; ++ks)
          acc[mt + 4][nt] = __builtin_amdgcn_mfma_f32_16x16x32_bf16(a[mt * 2 + ks], b0[nt * 2 + ks], acc[mt + 4][nt], 0, 0, 0);
    __builtin_amdgcn_s_setprio(0);
    // tile-end barrier = next tile's gate barrier
  }

  __syncthreads();  // quiesce before LDS reuse by epilogue

  if (OUT_F32) {
#pragma unroll
    for (int nt = 0; nt < 4; ++nt) {
      long coln = n0 + wn * 64 + nt * 16 + ln;
      float bv = bias[coln];
#pragma unroll
      for (int mt = 0; mt < 8; ++mt) {
        long rowb = m0 + wm * 128 + mt * 16 + quad * 4;
#pragma unroll
        for (int r = 0; r < 4; ++r)
          ((float*)Cv)[(rowb + r) * N + coln] = acc[mt][nt][r] + bv;
      }
    }
  } else {
    // bf16: wave-private LDS patch for full-line 16B stores
    u16* patch = &lds[wave * 2176];  // [16][136]
    float bv[4];
#pragma unroll
    for (int nt = 0; nt < 4; ++nt) bv[nt] = bias[n0 + wn * 64 + nt * 16 + ln];
#pragma unroll
    for (int mt = 0; mt < 8; ++mt) {
#pragma unroll
      for (int nt = 0; nt < 4; ++nt)
#pragma unroll
        for (int r = 0; r < 4; ++r)
          patch[(quad * 4 + r) * 136 + nt * 16 + ln] = f2b(acc[mt][nt][r] + bv[nt]);
      wait_lds();  // cross-lane LDS RAW
#pragma unroll
      for (int it = 0; it < 2; ++it) {
        int cid = it * 64 + lane;
        int row = cid >> 3, ch = cid & 7;
        uint4 v = *(const uint4*)&patch[row * 136 + ch * 8];
        *(uint4*)&((u16*)Cv)[(m0 + wm * 128 + mt * 16 + row) * (long)N + n0 + wn * 64 + ch * 8] = v;
      }
      wait_lds();  // patch reads retired before next mt overwrites
    }
  }
}

// ---------------- fused attention per (n, head) ----------------
// qkv row layout [1536]: head h cols [h*192, +192) = q|k|v of 64.
// Block = 4 waves; wave w, strip s handles q-rows [w*64+s*32, +32).
// LDS: Ks [256][64] + Vt [64][256] = 64 KB; P aliases Ks during PV (waves
// are locksteppped by __syncthreads; K re-staged between strips).
__global__ __launch_bounds__(256, 2) void attn_fused(const u16* __restrict__ qkv,
                                                     u16* __restrict__ out) {
  __shared__ alignas(16) u16 Ks[256 * 64];  // [j][64], 16B chunk c stored at c^(j&7)
  __shared__ alignas(16) u16 Vt[64 * 256];  // [d][256], chunk cj stored at cj^(((d>>3)^d)&7)
  const int h = blockIdx.x;
  const long n = blockIdx.y;
  const int tid = threadIdx.x;
  const int lane = tid & 63, wave = tid >> 6;
  const int quad = lane >> 4, ln = lane & 15;
  const u16* base = qkv + (n * 256) * 1536 + h * 192;

  // ---- stage K (coalesced 16B loads; swizzled 16B LDS writes, conflict-free) ----
  auto stageK = [&]() {
    int c = tid & 7, jb = tid >> 3;
#pragma unroll
    for (int rr = 0; rr < 8; ++rr) {
      int j = jb + rr * 32;
      uint4 v = *(const uint4*)(base + (long)j * 1536 + 64 + c * 8);
      *(uint4*)&Ks[j * 64 + ((c ^ (j & 7)) * 8)] = v;
    }
  };
  stageK();
  // ---- stage V^T (coalesced loads; scalar scatter, key=(p^i) -> conflict-free) ----
  {
    int p = tid & 7, jb = tid >> 3;
#pragma unroll
    for (int rr = 0; rr < 8; ++rr) {
      int j = jb + rr * 32;
      union { uint4 v; u16 e[8]; } u;
      u.v = *(const uint4*)(base + (long)j * 1536 + 128 + p * 8);
      int cj = j >> 3, jl = j & 7;
#pragma unroll
      for (int i = 0; i < 8; ++i) {
        int d = p * 8 + i;
        int key = (p ^ i) & 7;  // == ((d>>3)^d)&7
        Vt[d * 256 + ((cj ^ key) * 8) + jl] = u.e[i];
      }
    }
  }
  __syncthreads();

  u16* Pw = &Ks[wave * 2176];  // [16][136] u16, aliases Ks during PV phases
  f32x4 zero = {0.f, 0.f, 0.f, 0.f};

  for (int s = 0; s < 2; ++s) {
    const int row0 = wave * 64 + s * 32;
    // q A-frags from global (rows x 64B lines, read once — coalesced)
    bf16x8 qa[2][2];
#pragma unroll
    for (int mt = 0; mt < 2; ++mt)
#pragma unroll
      for (int kc = 0; kc < 2; ++kc)
        qa[mt][kc] = ld_frag(base + (long)(row0 + mt * 16 + ln) * 1536 + kc * 32 + quad * 8);

    f32x4 sacc[2][16];
#pragma unroll
    for (int mt = 0; mt < 2; ++mt)
#pragma unroll
      for (int jt = 0; jt < 16; ++jt) sacc[mt][jt] = zero;

    // S = q k^T, kb from swizzled LDS
#pragma unroll
    for (int jt = 0; jt < 16; ++jt) {
#pragma unroll
      for (int kc = 0; kc < 2; ++kc) {
        bf16x8 kb = ld_frag(&Ks[(jt * 16 + ln) * 64 + (((kc * 4 + quad) ^ (ln & 7)) * 8)]);
        sacc[0][jt] = __builtin_amdgcn_mfma_f32_16x16x32_bf16(qa[0][kc], kb, sacc[0][jt], 0, 0, 0);
        sacc[1][jt] = __builtin_amdgcn_mfma_f32_16x16x32_bf16(qa[1][kc], kb, sacc[1][jt], 0, 0, 0);
      }
    }
    __syncthreads();  // all waves done reading Ks -> P may alias it

#pragma unroll
    for (int mt = 0; mt < 2; ++mt) {
      // softmax over j (rows at quad*4+r, cols at jt*16+ln)
      float linv[4];
#pragma unroll
      for (int r = 0; r < 4; ++r) {
        float mx = -3.0e38f;
#pragma unroll
        for (int jt = 0; jt < 16; ++jt) mx = fmaxf(mx, sacc[mt][jt][r]);
        mx = fmaxf(mx, __shfl_xor(mx, 1));
        mx = fmaxf(mx, __shfl_xor(mx, 2));
        mx = fmaxf(mx, __shfl_xor(mx, 4));
        mx = fmaxf(mx, __shfl_xor(mx, 8));
        float l = 0.f;
#pragma unroll
        for (int jt = 0; jt < 16; ++jt) {
          float p = __expf((sacc[mt][jt][r] - mx) * 0.125f);  // 1/sqrt(dh)
          sacc[mt][jt][r] = p;
          l += p;
        }
        l += __shfl_xor(l, 1);
        l += __shfl_xor(l, 2);
        l += __shfl_xor(l, 4);
        l += __shfl_xor(l, 8);
        linv[r] = 1.0f / l;
      }

      // O = P V in two j-halves of 128 (P buffer reused; oacc accumulates)
      f32x4 oacc[4];
#pragma unroll
      for (int dt = 0; dt < 4; ++dt) oacc[dt] = zero;
#pragma unroll
      for (int jh = 0; jh < 2; ++jh) {
#pragma unroll
        for (int jl = 0; jl < 8; ++jl) {
          int jt = jh * 8 + jl;
#pragma unroll
          for (int r = 0; r < 4; ++r)
            Pw[(quad * 4 + r) * 136 + jl * 16 + ln] = f2b(sacc[mt][jt][r]);
        }
        wait_lds();  // cross-lane LDS RAW
#pragma unroll
        for (int jcl = 0; jcl < 4; ++jcl) {
          bf16x8 pa = ld_frag(&Pw[ln * 136 + jcl * 32 + quad * 8]);
          int cjb = (jh * 4 + jcl) * 4 + quad;
#pragma unroll
          for (int dt = 0; dt < 4; ++dt) {
            int d = dt * 16 + ln;
            int key = ((d >> 3) ^ d) & 7;
            bf16x8 vb = ld_frag(&Vt[d * 256 + ((cjb ^ key) * 8)]);
            oacc[dt] = __builtin_amdgcn_mfma_f32_16x16x32_bf16(pa, vb, oacc[dt], 0, 0, 0);
          }
        }
      }
      // stage O tile (16 x 64) into Pw, then coalesced 16B global stores
#pragma unroll
      for (int dt = 0; dt < 4; ++dt)
#pragma unroll
        for (int r = 0; r < 4; ++r)
          Pw[(quad * 4 + r) * 136 + dt * 16 + ln] = f2b(oacc[dt][r] * linv[r]);
      wait_lds();
#pragma unroll
      for (int it = 0; it < 2; ++it) {
        int cid = it * 64 + lane;
        int row = cid >> 3, ch = cid & 7;
        uint4 v = *(const uint4*)&Pw[row * 136 + ch * 8];
        *(uint4*)&out[(n * 256 + row0 + mt * 16 + row) * 512 + h * 64 + ch * 8] = v;
      }
    }
    __syncthreads();  // P region quiesced
    if (s == 0) {
      stageK();       // restore K for strip 1
      __syncthreads();
    }
  }
}

extern "C" void kernel_launch(void* const* d_in, const int* in_sizes, int n_in,
                              void* d_out, int out_size, void* d_ws, size_t ws_size,
                              hipStream_t stream) {
  const float* x      = (const float*)d_in[0];  // [65536][512] fp32
  const float* w_qkv  = (const float*)d_in[1];  // [512][1536]
  const float* b_qkv  = (const float*)d_in[2];  // [1536]
  const float* w_proj = (const float*)d_in[3];  // [512][512]
  const float* b_proj = (const float*)d_in[4];  // [512]
  float* out = (float*)d_out;                   // [65536][512] fp32

  char* ws = (char*)d_ws;
  u16* xb   = (u16*)ws;                                         // 64 MiB
  u16* qkv  = (u16*)(ws + 67108864L);                           // 192 MiB
  u16* attn = (u16*)(ws + 67108864L + 201326592L);              // 64 MiB
  u16* Wt1  = (u16*)(ws + 67108864L + 201326592L + 67108864L);  // 1536x512
  u16* Wt2  = Wt1 + 1536 * 512;                                 // 512x512

  convert_f32_bf16<<<16384, 256, 0, stream>>>(x, xb);
  transpose_w<<<dim3(24, 8), 256, 0, stream>>>(w_qkv, Wt1, 512, 1536);
  transpose_w<<<dim3(8, 8), 256, 0, stream>>>(w_proj, Wt2, 512, 512);
  // grids: (M/256)*(N/256) blocks, both % 8 == 0 (bijective XCD swizzle)
  gemm_pipe<false><<<dim3(6 * 256), 512, 0, stream>>>(xb, Wt1, b_qkv, qkv, 65536, 1536, 512);
  attn_fused<<<dim3(8, 256), 256, 0, stream>>>(qkv, attn);
  gemm_pipe<true><<<dim3(2 * 256), 512, 0, stream>>>(attn, Wt2, b_proj, out, 65536, 512, 512);
}